// Round 1
// 844.122 us; speedup vs baseline: 1.0829x; 1.0829x over previous
//
#include <hip/hip_runtime.h>
#include <math.h>

#define NNODES 100000
#define NEDGES 1600000
#define FEAT 256
#define HID 128
#define NCLS 64
#define RPB 512                 // rows per bucket
#define NBG 196                 // buckets per graph = ceil(100000/512)
#define NB3 (3 * NBG)           // 588
#define CAP 8832                // per-bucket edge capacity (mean 8192 + 7 sigma)
#define SC_CHUNK 8192           // edges per scatter block (LDS-staged)
#define SC_THREADS 1024         // 16 waves/block

typedef __attribute__((ext_vector_type(8))) short bf16x8;
typedef __attribute__((ext_vector_type(4))) float f32x4;

__device__ __forceinline__ float bf2f(unsigned int u16) {
  union { unsigned int i; float f; } c; c.i = u16 << 16; return c.f;
}
__device__ __forceinline__ unsigned short f2bf(float f) {
  union { float f; unsigned int i; } c; c.f = f;
  unsigned int u = c.i;
  return (unsigned short)((u + 0x7fffu + ((u >> 16) & 1u)) >> 16);  // RNE
}

// ---------------- bucket histogram: bhist[g*NBG + (row>>9)] ----------------
__global__ __launch_bounds__(256) void k_bhist(const int* __restrict__ r0,
                                               const int* __restrict__ r1,
                                               const int* __restrict__ r2,
                                               int* __restrict__ bhist) {
  __shared__ int h[NBG];
  int g = blockIdx.y;
  const int* rr = (g == 0) ? r0 : (g == 1 ? r1 : r2);
  int tid = threadIdx.x;
  for (int i = tid; i < NBG; i += 256) h[i] = 0;
  __syncthreads();
  int base = blockIdx.x * 4096;
#pragma unroll
  for (int k = 0; k < 16; k++) {
    int e = base + k * 256 + tid;
    if (e < NEDGES) atomicAdd(&h[rr[e] >> 9], 1);
  }
  __syncthreads();
  for (int i = tid; i < NBG; i += 256)
    if (h[i]) atomicAdd(&bhist[g * NBG + i], h[i]);
}

// single-block exclusive scan over NB3 bucket counts -> boff[0..NB3]
__global__ __launch_bounds__(1024) void k_bscan(const int* __restrict__ bhist,
                                                int* __restrict__ boff) {
  __shared__ int sd[2][1024];
  int tid = threadIdx.x;
  int v = (tid < NB3) ? bhist[tid] : 0;
  sd[0][tid] = v;
  __syncthreads();
  int cur = 0;
  for (int off = 1; off < 1024; off <<= 1) {
    int nv = sd[cur][tid];
    if (tid >= off) nv += sd[cur][tid - off];
    sd[cur ^ 1][tid] = nv;
    __syncthreads();
    cur ^= 1;
  }
  int incl = sd[cur][tid];
  if (tid < NB3) boff[tid] = incl - v;
  if (tid == NB3 - 1) boff[NB3] = incl;
}

// ---------------- pass A: coarse bucket scatter (LDS-staged, coalesced writes) ---
// Each block: load 8192 edges into registers, LDS-hist, scan, scatter into LDS
// staging buffer ordered by bucket, then stream the buffer out linearly.
// Global write instructions now touch ~2 coalesced segments/wave instead of 64
// scattered cachelines -> ~8x fewer L2 write requests.
__global__ __launch_bounds__(SC_THREADS) void k_bucket_scatter(
    const int* __restrict__ r0, const int* __restrict__ r1, const int* __restrict__ r2,
    const int* __restrict__ c0, const int* __restrict__ c1, const int* __restrict__ c2,
    const float* __restrict__ v0, const float* __restrict__ v1, const float* __restrict__ v2,
    int* __restrict__ gcur, int2* __restrict__ edges) {
  __shared__ int2 stage[SC_CHUNK];            // 64 KB
  __shared__ unsigned char bid[SC_CHUNK];     // 8 KB  (NBG=196 < 256)
  __shared__ int hist[NBG];
  __shared__ int lbase[NBG];
  __shared__ int gstart[NBG];
  __shared__ int cur[NBG];
  __shared__ int sd[2][256];
  int g = blockIdx.y;
  const int*   rr = (g == 0) ? r0 : (g == 1 ? r1 : r2);
  const int*   cc = (g == 0) ? c0 : (g == 1 ? c1 : c2);
  const float* vv = (g == 0) ? v0 : (g == 1 ? v1 : v2);
  int tid = threadIdx.x;
  int base = blockIdx.x * SC_CHUNK;
  int cnt_blk = NEDGES - base;
  if (cnt_blk > SC_CHUNK) cnt_blk = SC_CHUNK;

  for (int i = tid; i < NBG; i += SC_THREADS) hist[i] = 0;
  __syncthreads();

  // load chunk into registers (single global read of r/c/v) + histogram
  int rowv[SC_CHUNK / SC_THREADS];
  int colv[SC_CHUNK / SC_THREADS];
  float valv[SC_CHUNK / SC_THREADS];
#pragma unroll
  for (int k = 0; k < SC_CHUNK / SC_THREADS; k++) {
    int e = base + k * SC_THREADS + tid;
    bool ok = e < NEDGES;
    rowv[k] = ok ? rr[e] : -1;
    colv[k] = ok ? cc[e] : 0;
    valv[k] = ok ? vv[e] : 0.f;
    if (ok) atomicAdd(&hist[rowv[k] >> 9], 1);
  }
  __syncthreads();

  // exclusive scan of 196 bucket counts (256-lane Hillis-Steele)
  if (tid < 256) sd[0][tid] = (tid < NBG) ? hist[tid] : 0;
  __syncthreads();
  int c = 0;
  for (int off = 1; off < 256; off <<= 1) {
    if (tid < 256) {
      int nv = sd[c][tid];
      if (tid >= off) nv += sd[c][tid - off];
      sd[c ^ 1][tid] = nv;
    }
    __syncthreads();
    c ^= 1;
  }
  if (tid < NBG) {
    int cn = hist[tid];
    int excl = sd[c][tid] - cn;
    lbase[tid] = excl;
    cur[tid] = excl;
    gstart[tid] = cn ? atomicAdd(&gcur[g * NBG + tid], cn) : 0;
  }
  __syncthreads();

  // scatter registers -> LDS staging (bucket-ordered), record bucket id per slot
#pragma unroll
  for (int k = 0; k < SC_CHUNK / SC_THREADS; k++) {
    if (rowv[k] >= 0) {
      int b = rowv[k] >> 9;
      int p = atomicAdd(&cur[b], 1);
      stage[p] = make_int2(((rowv[k] & (RPB - 1)) << 17) | colv[k], __float_as_int(valv[k]));
      bid[p] = (unsigned char)b;
    }
  }
  __syncthreads();

  // linear sweep -> coalesced global writes (runs of ~42 same-bucket slots)
  for (int i = tid; i < cnt_blk; i += SC_THREADS) {
    int b = bid[i];
    int dst = gstart[b] + (i - lbase[b]);
    edges[dst] = stage[i];
  }
}

// ---------------- pass B: in-bucket counting sort (LDS scatter, coalesced IO) ---
__global__ __launch_bounds__(512) void k_bucket_sort(const int* __restrict__ boff,
                                                     int2* __restrict__ edges,
                                                     int* __restrict__ row_ptr_all) {
  __shared__ int2 stage[CAP];   // 70.7 KB
  __shared__ int hist[RPB];
  __shared__ int sd[2][RPB];
  __shared__ int cur[RPB];
  int g = blockIdx.y, b = blockIdx.x;
  int tid = threadIdx.x;
  int idx = g * NBG + b;
  int base = boff[idx];
  int count = boff[idx + 1] - base;
  if (count > CAP) count = CAP;  // statistically impossible; memory-safety clamp
  hist[tid] = 0;
  __syncthreads();

  // single coalesced read of the bucket into registers + row histogram
  const int KSL = (CAP + 511) / 512;   // 18 slots/thread
  int2 ev[KSL];
#pragma unroll
  for (int k = 0; k < KSL; k++) {
    int i = tid + k * 512;
    if (i < count) {
      ev[k] = edges[base + i];
      atomicAdd(&hist[ev[k].x >> 17], 1);
    }
  }
  __syncthreads();

  // exclusive scan of 512 row counts
  int v = hist[tid];
  sd[0][tid] = v;
  __syncthreads();
  int c2 = 0;
  for (int off = 1; off < 512; off <<= 1) {
    int nv = sd[c2][tid];
    if (tid >= off) nv += sd[c2][tid - off];
    sd[c2 ^ 1][tid] = nv;
    __syncthreads();
    c2 ^= 1;
  }
  int excl = sd[c2][tid] - v;
  int row = b * RPB + tid;
  if (row <= NNODES) row_ptr_all[g * (NNODES + 1) + row] = base + excl;
  cur[tid] = excl;
  __syncthreads();

  // scatter registers -> LDS in sorted position
#pragma unroll
  for (int k = 0; k < KSL; k++) {
    int i = tid + k * 512;
    if (i < count) {
      int lr = ev[k].x >> 17;
      int p = atomicAdd(&cur[lr], 1);
      stage[p] = make_int2(ev[k].x & 0x1FFFF, ev[k].y);
    }
  }
  __syncthreads();

  // fully coalesced writeback
  for (int i = tid; i < count; i += 512) edges[base + i] = stage[i];
}

// ---------------- prep ----------------
__global__ __launch_bounds__(256) void k_convert_bf16(const float* __restrict__ src,
                                                      unsigned short* __restrict__ dst,
                                                      int n4) {
  int i = blockIdx.x * blockDim.x + threadIdx.x;
  if (i < n4) {
    float4 v = ((const float4*)src)[i];
    ushort4 o;
    o.x = f2bf(v.x); o.y = f2bf(v.y); o.z = f2bf(v.z); o.w = f2bf(v.w);
    ((ushort4*)dst)[i] = o;
  }
}

__global__ __launch_bounds__(256) void k_transpose3(const float* __restrict__ s0,
                                                    const float* __restrict__ s1,
                                                    const float* __restrict__ s2,
                                                    unsigned short* __restrict__ d0,
                                                    unsigned short* __restrict__ d1,
                                                    unsigned short* __restrict__ d2,
                                                    int K, int N) {
  int g = blockIdx.y;
  const float* src = (g == 0) ? s0 : (g == 1 ? s1 : s2);
  unsigned short* dst = (g == 0) ? d0 : (g == 1 ? d1 : d2);
  int idx = blockIdx.x * 256 + threadIdx.x;
  if (idx < K * N) {
    int k = idx / N, n = idx % N;
    dst[(size_t)n * K + k] = f2bf(src[idx]);
  }
}

// ---------------- bf16 MFMA GEMMs (W tiny -> L1/L2 resident, no LDS) ----------------
__global__ __launch_bounds__(256) void k_gemm1(const unsigned short* __restrict__ A,
                                               const unsigned short* __restrict__ Wt,
                                               unsigned short* __restrict__ C, int M) {
  int tid = threadIdx.x;
  int wave = tid >> 6, lane = tid & 63;
  int quad = lane >> 4, r = lane & 15;
  int m0 = blockIdx.x * 128 + wave * 32;
  int ra0 = m0 + r;      if (ra0 >= M) ra0 = 0;
  int ra1 = m0 + 16 + r; if (ra1 >= M) ra1 = 0;
  const unsigned short* pa0 = A + (size_t)ra0 * FEAT + quad * 8;
  const unsigned short* pa1 = A + (size_t)ra1 * FEAT + quad * 8;
  f32x4 acc[2][8];
#pragma unroll
  for (int i = 0; i < 2; i++)
#pragma unroll
    for (int j = 0; j < 8; j++) acc[i][j] = (f32x4){0.f, 0.f, 0.f, 0.f};
  for (int k0 = 0; k0 < FEAT; k0 += 32) {
    bf16x8 a0 = *(const bf16x8*)(pa0 + k0);
    bf16x8 a1 = *(const bf16x8*)(pa1 + k0);
#pragma unroll
    for (int nt = 0; nt < 8; nt++) {
      bf16x8 b = *(const bf16x8*)(Wt + (size_t)(nt * 16 + r) * FEAT + k0 + quad * 8);
      acc[0][nt] = __builtin_amdgcn_mfma_f32_16x16x32_bf16(a0, b, acc[0][nt], 0, 0, 0);
      acc[1][nt] = __builtin_amdgcn_mfma_f32_16x16x32_bf16(a1, b, acc[1][nt], 0, 0, 0);
    }
  }
#pragma unroll
  for (int t = 0; t < 2; t++)
#pragma unroll
    for (int reg = 0; reg < 4; reg++) {
      int row = m0 + t * 16 + quad * 4 + reg;
      if (row < M) {
#pragma unroll
        for (int nt = 0; nt < 8; nt++)
          C[(size_t)row * HID + nt * 16 + r] = f2bf(acc[t][nt][reg]);
      }
    }
}

__global__ __launch_bounds__(256) void k_gemm2(const unsigned short* __restrict__ A,
                                               const unsigned short* __restrict__ Wt,
                                               unsigned short* __restrict__ C, int M) {
  int tid = threadIdx.x;
  int wave = tid >> 6, lane = tid & 63;
  int quad = lane >> 4, r = lane & 15;
  int m0 = blockIdx.x * 128 + wave * 32;
  int ra0 = m0 + r;      if (ra0 >= M) ra0 = 0;
  int ra1 = m0 + 16 + r; if (ra1 >= M) ra1 = 0;
  const unsigned short* pa0 = A + (size_t)ra0 * HID + quad * 8;
  const unsigned short* pa1 = A + (size_t)ra1 * HID + quad * 8;
  f32x4 acc[2][4];
#pragma unroll
  for (int i = 0; i < 2; i++)
#pragma unroll
    for (int j = 0; j < 4; j++) acc[i][j] = (f32x4){0.f, 0.f, 0.f, 0.f};
  for (int k0 = 0; k0 < HID; k0 += 32) {
    bf16x8 a0 = *(const bf16x8*)(pa0 + k0);
    bf16x8 a1 = *(const bf16x8*)(pa1 + k0);
#pragma unroll
    for (int nt = 0; nt < 4; nt++) {
      bf16x8 b = *(const bf16x8*)(Wt + (size_t)(nt * 16 + r) * HID + k0 + quad * 8);
      acc[0][nt] = __builtin_amdgcn_mfma_f32_16x16x32_bf16(a0, b, acc[0][nt], 0, 0, 0);
      acc[1][nt] = __builtin_amdgcn_mfma_f32_16x16x32_bf16(a1, b, acc[1][nt], 0, 0, 0);
    }
  }
#pragma unroll
  for (int t = 0; t < 2; t++)
#pragma unroll
    for (int reg = 0; reg < 4; reg++) {
      int row = m0 + t * 16 + quad * 4 + reg;
      if (row < M) {
#pragma unroll
        for (int nt = 0; nt < 4; nt++)
          C[(size_t)row * NCLS + nt * 16 + r] = f2bf(acc[t][nt][reg]);
      }
    }
}

// ---------------- SpMM (CSR), one wave/row, 16B/lane gathers ----------------
// Quarter-wave per edge: 16 lanes x dwordx4 = one 256B row; 4 edges per load instr.
__global__ __launch_bounds__(256) void k_spmm128_relu(const int* __restrict__ rp,
                                                      const int2* __restrict__ edges,
                                                      const unsigned short* __restrict__ dense,
                                                      unsigned short* __restrict__ out, int n) {
  int w = (blockIdx.x * blockDim.x + threadIdx.x) >> 6;
  int lane = threadIdx.x & 63;
  if (w >= n) return;
  int grp = lane >> 4;    // 0..3: edge slot within quad
  int sub = lane & 15;    // feats sub*8 .. sub*8+7
  int s = rp[w], e = rp[w + 1];
  float acc[8];
#pragma unroll
  for (int i = 0; i < 8; i++) acc[i] = 0.f;
  for (int j = s; j < e; j += 4) {
    int ej = j + grp;
    bool valid = ej < e;
    int2 ed = edges[valid ? ej : s];
    float v = valid ? __int_as_float(ed.y) : 0.f;
    bf16x8 u = *(const bf16x8*)(dense + (size_t)ed.x * 128 + sub * 8);
#pragma unroll
    for (int i = 0; i < 8; i++)
      acc[i] = fmaf(v, bf2f((unsigned short)u[i]), acc[i]);
  }
#pragma unroll
  for (int i = 0; i < 8; i++) {
    acc[i] += __shfl_xor(acc[i], 32, 64);
    acc[i] += __shfl_xor(acc[i], 16, 64);
    acc[i] = fmaxf(acc[i], 0.f);
  }
  if (lane < 16) {
    uint4 pk;
    pk.x = (unsigned int)f2bf(acc[0]) | ((unsigned int)f2bf(acc[1]) << 16);
    pk.y = (unsigned int)f2bf(acc[2]) | ((unsigned int)f2bf(acc[3]) << 16);
    pk.z = (unsigned int)f2bf(acc[4]) | ((unsigned int)f2bf(acc[5]) << 16);
    pk.w = (unsigned int)f2bf(acc[6]) | ((unsigned int)f2bf(acc[7]) << 16);
    *(uint4*)(out + (size_t)w * 128 + sub * 8) = pk;
  }
}

// Eighth-wave per edge: 8 lanes x dwordx4 = one 128B row; 8 edges per load instr.
// mode: 0 = write logits, 1 = accumulate, 2 = accumulate + fused log_softmax -> final_out
__global__ __launch_bounds__(256) void k_spmm64_gate(const int* __restrict__ rp,
                                                     const int2* __restrict__ edges,
                                                     const unsigned short* __restrict__ dense,
                                                     const float* __restrict__ bias,
                                                     const float* __restrict__ gate,
                                                     float* __restrict__ logits,
                                                     float* __restrict__ final_out,
                                                     int n, int mode, int one_minus) {
  int w = (blockIdx.x * blockDim.x + threadIdx.x) >> 6;
  int lane = threadIdx.x & 63;
  if (w >= n) return;
  int grp = lane >> 3;    // 0..7: edge slot
  int sub = lane & 7;     // classes sub*8 .. sub*8+7
  int s = rp[w], e = rp[w + 1];
  float acc[8];
#pragma unroll
  for (int i = 0; i < 8; i++) acc[i] = 0.f;
  for (int j = s; j < e; j += 8) {
    int ej = j + grp;
    bool valid = ej < e;
    int2 ed = edges[valid ? ej : s];
    float v = valid ? __int_as_float(ed.y) : 0.f;
    bf16x8 u = *(const bf16x8*)(dense + (size_t)ed.x * 64 + sub * 8);
#pragma unroll
    for (int i = 0; i < 8; i++)
      acc[i] = fmaf(v, bf2f((unsigned short)u[i]), acc[i]);
  }
#pragma unroll
  for (int i = 0; i < 8; i++) {
    acc[i] += __shfl_xor(acc[i], 32, 64);
    acc[i] += __shfl_xor(acc[i], 16, 64);
    acc[i] += __shfl_xor(acc[i], 8, 64);
  }
  float gv = gate[0];
  float scale = one_minus ? (1.0f - gv) : gv;
  float4 b0 = *(const float4*)(bias + sub * 8);
  float4 b1 = *(const float4*)(bias + sub * 8 + 4);
  float vc[8];
  vc[0] = scale * (acc[0] + b0.x); vc[1] = scale * (acc[1] + b0.y);
  vc[2] = scale * (acc[2] + b0.z); vc[3] = scale * (acc[3] + b0.w);
  vc[4] = scale * (acc[4] + b1.x); vc[5] = scale * (acc[5] + b1.y);
  vc[6] = scale * (acc[6] + b1.z); vc[7] = scale * (acc[7] + b1.w);
  size_t o = (size_t)w * 64 + sub * 8;
  if (mode == 0) {
    if (grp == 0) {
      *(float4*)(logits + o)     = make_float4(vc[0], vc[1], vc[2], vc[3]);
      *(float4*)(logits + o + 4) = make_float4(vc[4], vc[5], vc[6], vc[7]);
    }
  } else if (mode == 1) {
    float4 L0 = *(const float4*)(logits + o);
    float4 L1 = *(const float4*)(logits + o + 4);
    if (grp == 0) {
      *(float4*)(logits + o)     = make_float4(vc[0] + L0.x, vc[1] + L0.y, vc[2] + L0.z, vc[3] + L0.w);
      *(float4*)(logits + o + 4) = make_float4(vc[4] + L1.x, vc[5] + L1.y, vc[6] + L1.z, vc[7] + L1.w);
    }
  } else {
    float4 L0 = *(const float4*)(logits + o);
    float4 L1 = *(const float4*)(logits + o + 4);
    vc[0] += L0.x; vc[1] += L0.y; vc[2] += L0.z; vc[3] += L0.w;
    vc[4] += L1.x; vc[5] += L1.y; vc[6] += L1.z; vc[7] += L1.w;
    float m = vc[0];
#pragma unroll
    for (int i = 1; i < 8; i++) m = fmaxf(m, vc[i]);
    m = fmaxf(m, __shfl_xor(m, 1, 64));
    m = fmaxf(m, __shfl_xor(m, 2, 64));
    m = fmaxf(m, __shfl_xor(m, 4, 64));
    float sum = 0.f;
#pragma unroll
    for (int i = 0; i < 8; i++) sum += expf(vc[i] - m);
    sum += __shfl_xor(sum, 1, 64);
    sum += __shfl_xor(sum, 2, 64);
    sum += __shfl_xor(sum, 4, 64);
    float ls = m + logf(sum);
    if (grp == 0) {
      *(float4*)(final_out + o)     = make_float4(vc[0] - ls, vc[1] - ls, vc[2] - ls, vc[3] - ls);
      *(float4*)(final_out + o + 4) = make_float4(vc[4] - ls, vc[5] - ls, vc[6] - ls, vc[7] - ls);
    }
  }
}

extern "C" void kernel_launch(void* const* d_in, const int* in_sizes, int n_in,
                              void* d_out, int out_size, void* d_ws, size_t ws_size,
                              hipStream_t stream) {
  (void)in_sizes; (void)n_in; (void)out_size; (void)ws_size;
  const float* x = (const float*)d_in[0];
  const int*   rows[3]   = {(const int*)d_in[1], (const int*)d_in[4], (const int*)d_in[7]};
  const int*   colsIn[3] = {(const int*)d_in[2], (const int*)d_in[5], (const int*)d_in[8]};
  const float* valsIn[3] = {(const float*)d_in[3], (const float*)d_in[6], (const float*)d_in[9]};
  const float* Whid[3] = {(const float*)d_in[10], (const float*)d_in[13], (const float*)d_in[16]};
  const float* Wout[3] = {(const float*)d_in[11], (const float*)d_in[14], (const float*)d_in[17]};
  const float* bout[3] = {(const float*)d_in[12], (const float*)d_in[15], (const float*)d_in[18]};
  const float* gate = (const float*)d_in[19];
  float* out = (float*)d_out;

  const int N = NNODES, E = NEDGES;
  size_t off = 0;
  auto ws = [&](size_t bytes) {
    void* p = (char*)d_ws + off;
    off += (bytes + 255) & ~(size_t)255;
    return p;
  };
  unsigned short* x_bf = (unsigned short*)ws((size_t)N * FEAT * 2);
  unsigned short* Wt1[3], *Wt2[3];
  for (int g = 0; g < 3; g++) Wt1[g] = (unsigned short*)ws((size_t)HID * FEAT * 2);
  for (int g = 0; g < 3; g++) Wt2[g] = (unsigned short*)ws((size_t)NCLS * HID * 2);
  unsigned short* hsup   = (unsigned short*)ws((size_t)N * HID * 2);
  unsigned short* h1     = (unsigned short*)ws((size_t)N * HID * 2);
  float*          logits = (float*)         ws((size_t)N * NCLS * 4);
  unsigned short* h2     = hsup;  // gemm2 out aliases hsup (dead by then)
  int2* edges   = (int2*)ws((size_t)3 * E * 8);
  int*  rp_all  = (int*) ws((size_t)3 * (N + 1) * 4);
  int*  bhist   = (int*) ws(NB3 * 4);
  int*  boff    = (int*) ws((NB3 + 1) * 4);
  int*  gcur    = (int*) ws(NB3 * 4);

  dim3 b256(256);
  dim3 gRows((N + 3) / 4);
  dim3 gGemm((N + 127) / 128);

  // prep: x -> bf16; batched weight transposes
  k_convert_bf16<<<(N * FEAT / 4 + 255) / 256, b256, 0, stream>>>(x, x_bf, N * FEAT / 4);
  k_transpose3<<<dim3((FEAT * HID + 255) / 256, 3), b256, 0, stream>>>(
      Whid[0], Whid[1], Whid[2], Wt1[0], Wt1[1], Wt1[2], FEAT, HID);
  k_transpose3<<<dim3((HID * NCLS + 255) / 256, 3), b256, 0, stream>>>(
      Wout[0], Wout[1], Wout[2], Wt2[0], Wt2[1], Wt2[2], HID, NCLS);

  // CSR build: bucket hist -> scan -> coarse scatter -> in-bucket sort (+ row_ptr)
  hipMemsetAsync(bhist, 0, NB3 * 4, stream);
  k_bhist<<<dim3((E + 4095) / 4096, 3), b256, 0, stream>>>(rows[0], rows[1], rows[2], bhist);
  k_bscan<<<1, 1024, 0, stream>>>(bhist, boff);
  hipMemcpyAsync(gcur, boff, NB3 * 4, hipMemcpyDeviceToDevice, stream);
  k_bucket_scatter<<<dim3((E + SC_CHUNK - 1) / SC_CHUNK, 3), dim3(SC_THREADS), 0, stream>>>(
      rows[0], rows[1], rows[2], colsIn[0], colsIn[1], colsIn[2],
      valsIn[0], valsIn[1], valsIn[2], gcur, edges);
  k_bucket_sort<<<dim3(NBG, 3), 512, 0, stream>>>(boff, edges, rp_all);

  for (int g = 0; g < 3; g++) {
    const int* rp = rp_all + (size_t)g * (N + 1);
    k_gemm1<<<gGemm, b256, 0, stream>>>(x_bf, Wt1[g], hsup, N);
    k_spmm128_relu<<<gRows, b256, 0, stream>>>(rp, edges, hsup, h1, N);
    k_gemm2<<<gGemm, b256, 0, stream>>>(h1, Wt2[g], h2, N);
    k_spmm64_gate<<<gRows, b256, 0, stream>>>(rp, edges, h2, bout[g], gate, logits, out, N,
                                              /*mode=*/g, /*one_minus=*/(g != 0));
  }
}

// Round 2
// 727.597 us; speedup vs baseline: 1.2564x; 1.1602x over previous
//
#include <hip/hip_runtime.h>
#include <math.h>

#define NNODES 100000
#define NEDGES 1600000
#define FEAT 256
#define HID 128
#define NCLS 64
#define RPB 512                 // rows per bucket
#define NBG 196                 // buckets per graph = ceil(100000/512)
#define NB3 (3 * NBG)           // 588
#define CAP 8832                // per-bucket edge capacity (mean 8192 + 7 sigma)
#define SC_CHUNK 8192           // edges per scatter block (LDS-staged)
#define SC_THREADS 1024         // 16 waves/block

typedef __attribute__((ext_vector_type(8))) short bf16x8;
typedef __attribute__((ext_vector_type(4))) float f32x4;
typedef __attribute__((ext_vector_type(2))) float f32x2;

__device__ __forceinline__ float bf2f(unsigned int u16) {
  union { unsigned int i; float f; } c; c.i = u16 << 16; return c.f;
}
__device__ __forceinline__ unsigned short f2bf(float f) {
  union { float f; unsigned int i; } c; c.f = f;
  unsigned int u = c.i;
  return (unsigned short)((u + 0x7fffu + ((u >> 16) & 1u)) >> 16);  // RNE
}

// 8 bf16 (as uint4) * scalar-pair vv -> 4 packed f32x2 accumulators
__device__ __forceinline__ void fma8(const uint4 u, const f32x2 vv, f32x2* a) {
  f32x2 p0, p1, p2, p3;
  p0.x = __uint_as_float(u.x << 16); p0.y = __uint_as_float(u.x & 0xffff0000u);
  p1.x = __uint_as_float(u.y << 16); p1.y = __uint_as_float(u.y & 0xffff0000u);
  p2.x = __uint_as_float(u.z << 16); p2.y = __uint_as_float(u.z & 0xffff0000u);
  p3.x = __uint_as_float(u.w << 16); p3.y = __uint_as_float(u.w & 0xffff0000u);
  a[0] += p0 * vv; a[1] += p1 * vv; a[2] += p2 * vv; a[3] += p3 * vv;
}

// ---------------- bucket histogram: bhist[g*NBG + (row>>9)] ----------------
__global__ __launch_bounds__(256) void k_bhist(const int* __restrict__ r0,
                                               const int* __restrict__ r1,
                                               const int* __restrict__ r2,
                                               int* __restrict__ bhist) {
  __shared__ int h[NBG];
  int g = blockIdx.y;
  const int* rr = (g == 0) ? r0 : (g == 1 ? r1 : r2);
  int tid = threadIdx.x;
  for (int i = tid; i < NBG; i += 256) h[i] = 0;
  __syncthreads();
  int base = blockIdx.x * 4096;
#pragma unroll
  for (int k = 0; k < 16; k++) {
    int e = base + k * 256 + tid;
    if (e < NEDGES) atomicAdd(&h[rr[e] >> 9], 1);
  }
  __syncthreads();
  for (int i = tid; i < NBG; i += 256)
    if (h[i]) atomicAdd(&bhist[g * NBG + i], h[i]);
}

// single-block exclusive scan over NB3 bucket counts -> boff[0..NB3]
__global__ __launch_bounds__(1024) void k_bscan(const int* __restrict__ bhist,
                                                int* __restrict__ boff) {
  __shared__ int sd[2][1024];
  int tid = threadIdx.x;
  int v = (tid < NB3) ? bhist[tid] : 0;
  sd[0][tid] = v;
  __syncthreads();
  int cur = 0;
  for (int off = 1; off < 1024; off <<= 1) {
    int nv = sd[cur][tid];
    if (tid >= off) nv += sd[cur][tid - off];
    sd[cur ^ 1][tid] = nv;
    __syncthreads();
    cur ^= 1;
  }
  int incl = sd[cur][tid];
  if (tid < NB3) boff[tid] = incl - v;
  if (tid == NB3 - 1) boff[NB3] = incl;
}

// ---------------- pass A: coarse bucket scatter (LDS-staged, coalesced writes) ---
__global__ __launch_bounds__(SC_THREADS) void k_bucket_scatter(
    const int* __restrict__ r0, const int* __restrict__ r1, const int* __restrict__ r2,
    const int* __restrict__ c0, const int* __restrict__ c1, const int* __restrict__ c2,
    const float* __restrict__ v0, const float* __restrict__ v1, const float* __restrict__ v2,
    int* __restrict__ gcur, int2* __restrict__ edges) {
  __shared__ int2 stage[SC_CHUNK];            // 64 KB
  __shared__ unsigned char bid[SC_CHUNK];     // 8 KB  (NBG=196 < 256)
  __shared__ int hist[NBG];
  __shared__ int lbase[NBG];
  __shared__ int gstart[NBG];
  __shared__ int cur[NBG];
  __shared__ int sd[2][256];
  int g = blockIdx.y;
  const int*   rr = (g == 0) ? r0 : (g == 1 ? r1 : r2);
  const int*   cc = (g == 0) ? c0 : (g == 1 ? c1 : c2);
  const float* vv = (g == 0) ? v0 : (g == 1 ? v1 : v2);
  int tid = threadIdx.x;
  int base = blockIdx.x * SC_CHUNK;
  int cnt_blk = NEDGES - base;
  if (cnt_blk > SC_CHUNK) cnt_blk = SC_CHUNK;

  for (int i = tid; i < NBG; i += SC_THREADS) hist[i] = 0;
  __syncthreads();

  int rowv[SC_CHUNK / SC_THREADS];
  int colv[SC_CHUNK / SC_THREADS];
  float valv[SC_CHUNK / SC_THREADS];
#pragma unroll
  for (int k = 0; k < SC_CHUNK / SC_THREADS; k++) {
    int e = base + k * SC_THREADS + tid;
    bool ok = e < NEDGES;
    rowv[k] = ok ? rr[e] : -1;
    colv[k] = ok ? cc[e] : 0;
    valv[k] = ok ? vv[e] : 0.f;
    if (ok) atomicAdd(&hist[rowv[k] >> 9], 1);
  }
  __syncthreads();

  if (tid < 256) sd[0][tid] = (tid < NBG) ? hist[tid] : 0;
  __syncthreads();
  int c = 0;
  for (int off = 1; off < 256; off <<= 1) {
    if (tid < 256) {
      int nv = sd[c][tid];
      if (tid >= off) nv += sd[c][tid - off];
      sd[c ^ 1][tid] = nv;
    }
    __syncthreads();
    c ^= 1;
  }
  if (tid < NBG) {
    int cn = hist[tid];
    int excl = sd[c][tid] - cn;
    lbase[tid] = excl;
    cur[tid] = excl;
    gstart[tid] = cn ? atomicAdd(&gcur[g * NBG + tid], cn) : 0;
  }
  __syncthreads();

#pragma unroll
  for (int k = 0; k < SC_CHUNK / SC_THREADS; k++) {
    if (rowv[k] >= 0) {
      int b = rowv[k] >> 9;
      int p = atomicAdd(&cur[b], 1);
      stage[p] = make_int2(((rowv[k] & (RPB - 1)) << 17) | colv[k], __float_as_int(valv[k]));
      bid[p] = (unsigned char)b;
    }
  }
  __syncthreads();

  for (int i = tid; i < cnt_blk; i += SC_THREADS) {
    int b = bid[i];
    int dst = gstart[b] + (i - lbase[b]);
    edges[dst] = stage[i];
  }
}

// ---------------- pass B: in-bucket counting sort (LDS scatter, coalesced IO) ---
__global__ __launch_bounds__(512) void k_bucket_sort(const int* __restrict__ boff,
                                                     int2* __restrict__ edges,
                                                     int* __restrict__ row_ptr_all) {
  __shared__ int2 stage[CAP];   // 70.7 KB
  __shared__ int hist[RPB];
  __shared__ int sd[2][RPB];
  __shared__ int cur[RPB];
  int g = blockIdx.y, b = blockIdx.x;
  int tid = threadIdx.x;
  int idx = g * NBG + b;
  int base = boff[idx];
  int count = boff[idx + 1] - base;
  if (count > CAP) count = CAP;
  hist[tid] = 0;
  __syncthreads();

  const int KSL = (CAP + 511) / 512;   // 18 slots/thread
  int2 ev[KSL];
#pragma unroll
  for (int k = 0; k < KSL; k++) {
    int i = tid + k * 512;
    if (i < count) {
      ev[k] = edges[base + i];
      atomicAdd(&hist[ev[k].x >> 17], 1);
    }
  }
  __syncthreads();

  int v = hist[tid];
  sd[0][tid] = v;
  __syncthreads();
  int c2 = 0;
  for (int off = 1; off < 512; off <<= 1) {
    int nv = sd[c2][tid];
    if (tid >= off) nv += sd[c2][tid - off];
    sd[c2 ^ 1][tid] = nv;
    __syncthreads();
    c2 ^= 1;
  }
  int excl = sd[c2][tid] - v;
  int row = b * RPB + tid;
  if (row <= NNODES) row_ptr_all[g * (NNODES + 1) + row] = base + excl;
  cur[tid] = excl;
  __syncthreads();

#pragma unroll
  for (int k = 0; k < KSL; k++) {
    int i = tid + k * 512;
    if (i < count) {
      int lr = ev[k].x >> 17;
      int p = atomicAdd(&cur[lr], 1);
      stage[p] = make_int2(ev[k].x & 0x1FFFF, ev[k].y);
    }
  }
  __syncthreads();

  for (int i = tid; i < count; i += 512) edges[base + i] = stage[i];
}

// ---------------- prep ----------------
__global__ __launch_bounds__(256) void k_convert_bf16(const float* __restrict__ src,
                                                      unsigned short* __restrict__ dst,
                                                      int n4) {
  int i = blockIdx.x * blockDim.x + threadIdx.x;
  if (i < n4) {
    float4 v = ((const float4*)src)[i];
    ushort4 o;
    o.x = f2bf(v.x); o.y = f2bf(v.y); o.z = f2bf(v.z); o.w = f2bf(v.w);
    ((ushort4*)dst)[i] = o;
  }
}

__global__ __launch_bounds__(256) void k_transpose3(const float* __restrict__ s0,
                                                    const float* __restrict__ s1,
                                                    const float* __restrict__ s2,
                                                    unsigned short* __restrict__ d0,
                                                    unsigned short* __restrict__ d1,
                                                    unsigned short* __restrict__ d2,
                                                    int K, int N) {
  int g = blockIdx.y;
  const float* src = (g == 0) ? s0 : (g == 1 ? s1 : s2);
  unsigned short* dst = (g == 0) ? d0 : (g == 1 ? d1 : d2);
  int idx = blockIdx.x * 256 + threadIdx.x;
  if (idx < K * N) {
    int k = idx / N, n = idx % N;
    dst[(size_t)n * K + k] = f2bf(src[idx]);
  }
}

// ---------------- batched bf16 MFMA GEMMs ----------------
// gemm1: all 3 graphs in one dispatch, g-minor block swizzle so the 3 graphs'
// blocks read the same x_bf tile back-to-back -> 2/3 of A reads become L2 hits.
__global__ __launch_bounds__(256) void k_gemm1_b(const unsigned short* __restrict__ A,
                                                 const unsigned short* __restrict__ WtA,
                                                 unsigned short* __restrict__ C3, int M) {
  int bxy = blockIdx.x;
  int g = bxy % 3;
  int bx = bxy / 3;
  const unsigned short* Wt = WtA + (size_t)g * HID * FEAT;
  unsigned short* C = C3 + (size_t)g * M * HID;
  int tid = threadIdx.x;
  int wave = tid >> 6, lane = tid & 63;
  int quad = lane >> 4, r = lane & 15;
  int m0 = bx * 128 + wave * 32;
  int ra0 = m0 + r;      if (ra0 >= M) ra0 = 0;
  int ra1 = m0 + 16 + r; if (ra1 >= M) ra1 = 0;
  const unsigned short* pa0 = A + (size_t)ra0 * FEAT + quad * 8;
  const unsigned short* pa1 = A + (size_t)ra1 * FEAT + quad * 8;
  f32x4 acc[2][8];
#pragma unroll
  for (int i = 0; i < 2; i++)
#pragma unroll
    for (int j = 0; j < 8; j++) acc[i][j] = (f32x4){0.f, 0.f, 0.f, 0.f};
  for (int k0 = 0; k0 < FEAT; k0 += 32) {
    bf16x8 a0 = *(const bf16x8*)(pa0 + k0);
    bf16x8 a1 = *(const bf16x8*)(pa1 + k0);
#pragma unroll
    for (int nt = 0; nt < 8; nt++) {
      bf16x8 b = *(const bf16x8*)(Wt + (size_t)(nt * 16 + r) * FEAT + k0 + quad * 8);
      acc[0][nt] = __builtin_amdgcn_mfma_f32_16x16x32_bf16(a0, b, acc[0][nt], 0, 0, 0);
      acc[1][nt] = __builtin_amdgcn_mfma_f32_16x16x32_bf16(a1, b, acc[1][nt], 0, 0, 0);
    }
  }
#pragma unroll
  for (int t = 0; t < 2; t++)
#pragma unroll
    for (int reg = 0; reg < 4; reg++) {
      int row = m0 + t * 16 + quad * 4 + reg;
      if (row < M) {
#pragma unroll
        for (int nt = 0; nt < 8; nt++)
          C[(size_t)row * HID + nt * 16 + r] = f2bf(acc[t][nt][reg]);
      }
    }
}

__global__ __launch_bounds__(256) void k_gemm2_b(const unsigned short* __restrict__ A3,
                                                 const unsigned short* __restrict__ WtA,
                                                 unsigned short* __restrict__ C3, int M) {
  int g = blockIdx.y;
  const unsigned short* A = A3 + (size_t)g * M * HID;
  const unsigned short* Wt = WtA + (size_t)g * NCLS * HID;
  unsigned short* C = C3 + (size_t)g * M * NCLS;
  int tid = threadIdx.x;
  int wave = tid >> 6, lane = tid & 63;
  int quad = lane >> 4, r = lane & 15;
  int m0 = blockIdx.x * 128 + wave * 32;
  int ra0 = m0 + r;      if (ra0 >= M) ra0 = 0;
  int ra1 = m0 + 16 + r; if (ra1 >= M) ra1 = 0;
  const unsigned short* pa0 = A + (size_t)ra0 * HID + quad * 8;
  const unsigned short* pa1 = A + (size_t)ra1 * HID + quad * 8;
  f32x4 acc[2][4];
#pragma unroll
  for (int i = 0; i < 2; i++)
#pragma unroll
    for (int j = 0; j < 4; j++) acc[i][j] = (f32x4){0.f, 0.f, 0.f, 0.f};
  for (int k0 = 0; k0 < HID; k0 += 32) {
    bf16x8 a0 = *(const bf16x8*)(pa0 + k0);
    bf16x8 a1 = *(const bf16x8*)(pa1 + k0);
#pragma unroll
    for (int nt = 0; nt < 4; nt++) {
      bf16x8 b = *(const bf16x8*)(Wt + (size_t)(nt * 16 + r) * HID + k0 + quad * 8);
      acc[0][nt] = __builtin_amdgcn_mfma_f32_16x16x32_bf16(a0, b, acc[0][nt], 0, 0, 0);
      acc[1][nt] = __builtin_amdgcn_mfma_f32_16x16x32_bf16(a1, b, acc[1][nt], 0, 0, 0);
    }
  }
#pragma unroll
  for (int t = 0; t < 2; t++)
#pragma unroll
    for (int reg = 0; reg < 4; reg++) {
      int row = m0 + t * 16 + quad * 4 + reg;
      if (row < M) {
#pragma unroll
        for (int nt = 0; nt < 4; nt++)
          C[(size_t)row * NCLS + nt * 16 + r] = f2bf(acc[t][nt][reg]);
      }
    }
}

// ---------------- SpMM (CSR), batched over g (grid.y, g-major) ----------------
// Quarter-wave per edge, 2 edges in flight per lane-group, packed f32x2 FMA.
__global__ __launch_bounds__(256) void k_spmm128_b(const int* __restrict__ rp_all,
                                                   const int2* __restrict__ edges,
                                                   const unsigned short* __restrict__ dense3,
                                                   unsigned short* __restrict__ out3, int n) {
  int g = blockIdx.y;
  const int* rp = rp_all + (size_t)g * (NNODES + 1);
  const unsigned short* dense = dense3 + (size_t)g * NNODES * HID;
  unsigned short* out = out3 + (size_t)g * NNODES * HID;
  int w = (blockIdx.x * blockDim.x + threadIdx.x) >> 6;
  int lane = threadIdx.x & 63;
  if (w >= n) return;
  int grp = lane >> 4;    // 0..3
  int sub = lane & 15;    // feats sub*8 .. sub*8+7
  int s = rp[w], e = rp[w + 1];
  f32x2 a0[4], a1[4];
#pragma unroll
  for (int q = 0; q < 4; q++) { a0[q] = (f32x2){0.f, 0.f}; a1[q] = (f32x2){0.f, 0.f}; }
  for (int j = s; j < e; j += 8) {
    int e0 = j + grp, e1 = j + 4 + grp;
    bool k0 = e0 < e, k1 = e1 < e;
    int2 d0 = edges[k0 ? e0 : s];
    int2 d1 = edges[k1 ? e1 : s];
    uint4 u0 = *(const uint4*)(dense + (size_t)d0.x * HID + sub * 8);
    uint4 u1 = *(const uint4*)(dense + (size_t)d1.x * HID + sub * 8);
    float f0 = k0 ? __int_as_float(d0.y) : 0.f;
    float f1 = k1 ? __int_as_float(d1.y) : 0.f;
    f32x2 v0; v0.x = f0; v0.y = f0;
    f32x2 v1; v1.x = f1; v1.y = f1;
    fma8(u0, v0, a0);
    fma8(u1, v1, a1);
  }
  unsigned int pk[4];
#pragma unroll
  for (int q = 0; q < 4; q++) {
    float lo = a0[q].x + a1[q].x;
    float hi = a0[q].y + a1[q].y;
    lo += __shfl_xor(lo, 32, 64); lo += __shfl_xor(lo, 16, 64);
    hi += __shfl_xor(hi, 32, 64); hi += __shfl_xor(hi, 16, 64);
    lo = fmaxf(lo, 0.f); hi = fmaxf(hi, 0.f);
    pk[q] = (unsigned int)f2bf(lo) | ((unsigned int)f2bf(hi) << 16);
  }
  if (lane < 16) {
    uint4 o; o.x = pk[0]; o.y = pk[1]; o.z = pk[2]; o.w = pk[3];
    *(uint4*)(out + (size_t)w * HID + sub * 8) = o;
  }
}

// Eighth-wave per edge, 2 edges in flight; each graph writes its own scaled+biased
// partial logits (no read-modify-write chain).
__global__ __launch_bounds__(256) void k_spmm64_b(const int* __restrict__ rp_all,
                                                  const int2* __restrict__ edges,
                                                  const unsigned short* __restrict__ dense3,
                                                  const float* __restrict__ b0p,
                                                  const float* __restrict__ b1p,
                                                  const float* __restrict__ b2p,
                                                  const float* __restrict__ gate,
                                                  float* __restrict__ logits3, int n) {
  int g = blockIdx.y;
  const int* rp = rp_all + (size_t)g * (NNODES + 1);
  const unsigned short* dense = dense3 + (size_t)g * NNODES * NCLS;
  const float* bias = (g == 0) ? b0p : (g == 1 ? b1p : b2p);
  float* logits = logits3 + (size_t)g * NNODES * NCLS;
  int w = (blockIdx.x * blockDim.x + threadIdx.x) >> 6;
  int lane = threadIdx.x & 63;
  if (w >= n) return;
  int grp = lane >> 3;    // 0..7
  int sub = lane & 7;     // classes sub*8 .. sub*8+7
  int s = rp[w], e = rp[w + 1];
  f32x2 a0[4], a1[4];
#pragma unroll
  for (int q = 0; q < 4; q++) { a0[q] = (f32x2){0.f, 0.f}; a1[q] = (f32x2){0.f, 0.f}; }
  for (int j = s; j < e; j += 16) {
    int e0 = j + grp, e1 = j + 8 + grp;
    bool k0 = e0 < e, k1 = e1 < e;
    int2 d0 = edges[k0 ? e0 : s];
    int2 d1 = edges[k1 ? e1 : s];
    uint4 u0 = *(const uint4*)(dense + (size_t)d0.x * NCLS + sub * 8);
    uint4 u1 = *(const uint4*)(dense + (size_t)d1.x * NCLS + sub * 8);
    float f0 = k0 ? __int_as_float(d0.y) : 0.f;
    float f1 = k1 ? __int_as_float(d1.y) : 0.f;
    f32x2 v0; v0.x = f0; v0.y = f0;
    f32x2 v1; v1.x = f1; v1.y = f1;
    fma8(u0, v0, a0);
    fma8(u1, v1, a1);
  }
  float gv = gate[0];
  float scale = (g == 0) ? gv : (1.0f - gv);
  float vc[8];
#pragma unroll
  for (int q = 0; q < 4; q++) {
    float lo = a0[q].x + a1[q].x;
    float hi = a0[q].y + a1[q].y;
    lo += __shfl_xor(lo, 32, 64); lo += __shfl_xor(lo, 16, 64); lo += __shfl_xor(lo, 8, 64);
    hi += __shfl_xor(hi, 32, 64); hi += __shfl_xor(hi, 16, 64); hi += __shfl_xor(hi, 8, 64);
    vc[2 * q] = lo; vc[2 * q + 1] = hi;
  }
  if (grp == 0) {
    float4 b0 = *(const float4*)(bias + sub * 8);
    float4 b1 = *(const float4*)(bias + sub * 8 + 4);
    size_t o = (size_t)w * NCLS + sub * 8;
    *(float4*)(logits + o) = make_float4(scale * (vc[0] + b0.x), scale * (vc[1] + b0.y),
                                         scale * (vc[2] + b0.z), scale * (vc[3] + b0.w));
    *(float4*)(logits + o + 4) = make_float4(scale * (vc[4] + b1.x), scale * (vc[5] + b1.y),
                                             scale * (vc[6] + b1.z), scale * (vc[7] + b1.w));
  }
}

// sum 3 partial logits + fused log_softmax -> final output
__global__ __launch_bounds__(256) void k_final(const float* __restrict__ l3,
                                               float* __restrict__ outp, int n) {
  int t = blockIdx.x * 256 + threadIdx.x;
  int w = t >> 3, sub = t & 7;
  if (w >= n) return;
  size_t o = (size_t)w * NCLS + sub * 8;
  const float* p0 = l3 + o;
  const float* p1 = l3 + (size_t)NNODES * NCLS + o;
  const float* p2 = l3 + (size_t)2 * NNODES * NCLS + o;
  float4 x0 = *(const float4*)p0, x1 = *(const float4*)(p0 + 4);
  float4 y0 = *(const float4*)p1, y1 = *(const float4*)(p1 + 4);
  float4 z0 = *(const float4*)p2, z1 = *(const float4*)(p2 + 4);
  float v[8];
  v[0] = x0.x + y0.x + z0.x; v[1] = x0.y + y0.y + z0.y;
  v[2] = x0.z + y0.z + z0.z; v[3] = x0.w + y0.w + z0.w;
  v[4] = x1.x + y1.x + z1.x; v[5] = x1.y + y1.y + z1.y;
  v[6] = x1.z + y1.z + z1.z; v[7] = x1.w + y1.w + z1.w;
  float m = v[0];
#pragma unroll
  for (int i = 1; i < 8; i++) m = fmaxf(m, v[i]);
  m = fmaxf(m, __shfl_xor(m, 1, 64));
  m = fmaxf(m, __shfl_xor(m, 2, 64));
  m = fmaxf(m, __shfl_xor(m, 4, 64));
  float sum = 0.f;
#pragma unroll
  for (int i = 0; i < 8; i++) sum += expf(v[i] - m);
  sum += __shfl_xor(sum, 1, 64);
  sum += __shfl_xor(sum, 2, 64);
  sum += __shfl_xor(sum, 4, 64);
  float ls = m + logf(sum);
  *(float4*)(outp + o)     = make_float4(v[0] - ls, v[1] - ls, v[2] - ls, v[3] - ls);
  *(float4*)(outp + o + 4) = make_float4(v[4] - ls, v[5] - ls, v[6] - ls, v[7] - ls);
}

extern "C" void kernel_launch(void* const* d_in, const int* in_sizes, int n_in,
                              void* d_out, int out_size, void* d_ws, size_t ws_size,
                              hipStream_t stream) {
  (void)in_sizes; (void)n_in; (void)out_size; (void)ws_size;
  const float* x = (const float*)d_in[0];
  const int*   rows[3]   = {(const int*)d_in[1], (const int*)d_in[4], (const int*)d_in[7]};
  const int*   colsIn[3] = {(const int*)d_in[2], (const int*)d_in[5], (const int*)d_in[8]};
  const float* valsIn[3] = {(const float*)d_in[3], (const float*)d_in[6], (const float*)d_in[9]};
  const float* Whid[3] = {(const float*)d_in[10], (const float*)d_in[13], (const float*)d_in[16]};
  const float* Wout[3] = {(const float*)d_in[11], (const float*)d_in[14], (const float*)d_in[17]};
  const float* bout[3] = {(const float*)d_in[12], (const float*)d_in[15], (const float*)d_in[18]};
  const float* gate = (const float*)d_in[19];
  float* out = (float*)d_out;

  const int N = NNODES, E = NEDGES;
  size_t off = 0;
  auto ws = [&](size_t bytes) {
    void* p = (char*)d_ws + off;
    off += (bytes + 255) & ~(size_t)255;
    return p;
  };
  // Region R1 (76.8 MB): x_bf (51.2 MB) early; h1[3] / logits3 later (aliased).
  // Lifetimes: x_bf dies after gemm1_b; h1[g] dies after gemm2_b reads it; then
  // the same 25.6 MB/g slot holds logits3[g] (N*HID*2 == N*NCLS*4).
  unsigned short* R1 = (unsigned short*)ws((size_t)3 * N * HID * 2);
  unsigned short* x_bf = R1;
  unsigned short* h13  = R1;
  float*          logits3 = (float*)R1;
  // hsup3: gemm1_b output; later reused as gemm2_b output (h2) per g.
  unsigned short* hsup3 = (unsigned short*)ws((size_t)3 * N * HID * 2);
  unsigned short* Wt1a = (unsigned short*)ws((size_t)3 * HID * FEAT * 2);
  unsigned short* Wt2a = (unsigned short*)ws((size_t)3 * NCLS * HID * 2);
  int2* edges   = (int2*)ws((size_t)3 * E * 8);
  int*  rp_all  = (int*) ws((size_t)3 * (N + 1) * 4);
  int*  bhist   = (int*) ws(NB3 * 4);
  int*  boff    = (int*) ws((NB3 + 1) * 4);
  int*  gcur    = (int*) ws(NB3 * 4);

  dim3 b256(256);
  dim3 gRows3((N + 3) / 4, 3);
  int nbGemm = (N + 127) / 128;

  // prep: x -> bf16; batched weight transposes (into contiguous Wt blocks)
  k_convert_bf16<<<(N * FEAT / 4 + 255) / 256, b256, 0, stream>>>(x, x_bf, N * FEAT / 4);
  k_transpose3<<<dim3((FEAT * HID + 255) / 256, 3), b256, 0, stream>>>(
      Whid[0], Whid[1], Whid[2], Wt1a, Wt1a + (size_t)HID * FEAT, Wt1a + (size_t)2 * HID * FEAT,
      FEAT, HID);
  k_transpose3<<<dim3((HID * NCLS + 255) / 256, 3), b256, 0, stream>>>(
      Wout[0], Wout[1], Wout[2], Wt2a, Wt2a + (size_t)NCLS * HID, Wt2a + (size_t)2 * NCLS * HID,
      HID, NCLS);

  // CSR build: bucket hist -> scan -> coarse scatter -> in-bucket sort (+ row_ptr)
  hipMemsetAsync(bhist, 0, NB3 * 4, stream);
  k_bhist<<<dim3((E + 4095) / 4096, 3), b256, 0, stream>>>(rows[0], rows[1], rows[2], bhist);
  k_bscan<<<1, 1024, 0, stream>>>(bhist, boff);
  hipMemcpyAsync(gcur, boff, NB3 * 4, hipMemcpyDeviceToDevice, stream);
  k_bucket_scatter<<<dim3((E + SC_CHUNK - 1) / SC_CHUNK, 3), dim3(SC_THREADS), 0, stream>>>(
      rows[0], rows[1], rows[2], colsIn[0], colsIn[1], colsIn[2],
      valsIn[0], valsIn[1], valsIn[2], gcur, edges);
  k_bucket_sort<<<dim3(NBG, 3), 512, 0, stream>>>(boff, edges, rp_all);

  // batched pipeline: 1 dispatch per stage, all 3 graphs each
  k_gemm1_b<<<dim3(3 * nbGemm), b256, 0, stream>>>(x_bf, Wt1a, hsup3, N);
  k_spmm128_b<<<gRows3, b256, 0, stream>>>(rp_all, edges, hsup3, h13, N);
  k_gemm2_b<<<dim3(nbGemm, 3), b256, 0, stream>>>(h13, Wt2a, hsup3, N);
  k_spmm64_b<<<gRows3, b256, 0, stream>>>(rp_all, edges, hsup3, bout[0], bout[1], bout[2],
                                          gate, logits3, N);
  k_final<<<(N * 8 + 255) / 256, b256, 0, stream>>>(logits3, out, N);
}